// Round 4
// baseline (202.467 us; speedup 1.0000x reference)
//
#include <hip/hip_runtime.h>

// Problem constants (match reference)
#define HH 256
#define WW 256
#define NPIX (HH * WW)        // 65536
#define NP 512                // points
// ALPHA = -5.0, 1/ALPHA = -0.2

// term2 decomposition: each block = 2 consecutive points x one 32-row slice
#define PPB 2
#define SLICE_ROWS 32
#define NSLICES (HH / SLICE_ROWS)          // 8
#define NPGRP (NP / PPB)                   // 256
#define NB_T2 (NPGRP * NSLICES)            // 2048
#define NB_T1 (NPIX / 256)                 // 256
#define NB_TOTAL (NB_T2 + NB_T1)           // 2304

// ws float layout: [0]=SUM1  [1]=SUM2  [2]=counter(uint)  [3..3+NP)=S[p]
#define WS_SUM1 0
#define WS_SUM2 1
#define WS_CNT  2
#define WS_S    3

__global__ __launch_bounds__(256) void whd_fused_kernel(const float* __restrict__ hm,
                                                        const float* __restrict__ pts,
                                                        float* __restrict__ ws,
                                                        float* __restrict__ out) {
    const int tid = threadIdx.x;
    const int bid = blockIdx.x;
    __shared__ float lred[PPB][4];
    __shared__ float dred[4];
    __shared__ unsigned lastflag;

    if (bid < NB_T2) {
        // ---------------- term 2: soft-min accumulation ----------------
        // dmax recomputed per block (cheap): max over the integer grid is at a
        // corner; d^2 separable.
        float m = 0.f;
        #pragma unroll
        for (int t = 0; t < 2; ++t) {
            int p = tid + t * 256;
            float py = pts[2 * p], px = pts[2 * p + 1];
            float my = fmaxf(py * py, (255.f - py) * (255.f - py));
            float mx = fmaxf(px * px, (255.f - px) * (255.f - px));
            m = fmaxf(m, my + mx);
        }
        #pragma unroll
        for (int off = 32; off; off >>= 1) m = fmaxf(m, __shfl_down(m, off, 64));
        if ((tid & 63) == 0) dred[tid >> 6] = m;
        __syncthreads();
        const float dmax = __builtin_amdgcn_sqrtf(
            fmaxf(fmaxf(dred[0], dred[1]), fmaxf(dred[2], dred[3])));

        const int pgrp  = bid & (NPGRP - 1);
        const int slice = bid >> 8;            // NPGRP = 256
        const int p0    = pgrp * PPB;

        float py[PPB], px[PPB];
        #pragma unroll
        for (int a = 0; a < PPB; ++a) {        // uniform -> SGPR loads
            py[a] = pts[2 * (p0 + a)];
            px[a] = pts[2 * (p0 + a) + 1];
        }

        // thread owns cols col0..col0+3 of rows {slice*32 + (tid>>6) + 4k}
        const float col0 = (float)((tid & 63) << 2);
        float dx2[PPB][4];
        #pragma unroll
        for (int a = 0; a < PPB; ++a)
            #pragma unroll
            for (int c = 0; c < 4; ++c) {
                float dx = col0 + (float)c - px[a];
                dx2[a][c] = dx * dx;
            }

        const float4* hm4 = (const float4*)hm;
        const int   gbase   = slice * (SLICE_ROWS * WW / 4) + tid;
        const float rowbase = (float)(slice * SLICE_ROWS + (tid >> 6));
        float acc[PPB] = {0.f, 0.f};

        float4 cur = hm4[gbase];
        #pragma unroll
        for (int k = 0; k < 8; ++k) {
            float4 nxt;
            if (k < 7) nxt = hm4[gbase + (k + 1) * 256];   // prefetch next 4 rows
            const float row = rowbase + (float)(4 * k);
            const float hx[4] = {cur.x, cur.y, cur.z, cur.w};

            // stage 0: constants per c
            float ct[4];
            #pragma unroll
            for (int c = 0; c < 4; ++c) ct[c] = fmaf(-hx[c], dmax, dmax); // (1-h)*dmax

            float dy2[PPB];
            #pragma unroll
            for (int a = 0; a < PPB; ++a) { float dy = row - py[a]; dy2[a] = dy * dy; }

            // stage 1: all distances (raw v_sqrt, 8-wide ILP)
            float s_[PPB][4];
            #pragma unroll
            for (int a = 0; a < PPB; ++a)
                #pragma unroll
                for (int c = 0; c < 4; ++c)
                    s_[a][c] = __builtin_amdgcn_sqrtf(dy2[a] + dx2[a][c]);

            // stage 2: all weights
            float w_[PPB][4];
            #pragma unroll
            for (int a = 0; a < PPB; ++a)
                #pragma unroll
                for (int c = 0; c < 4; ++c)
                    w_[a][c] = fmaf(hx[c], s_[a][c], ct[c]);

            // stage 3: Montgomery batch inversion (4 inverses per v_rcp),
            // then w^-5 accumulate
            #pragma unroll
            for (int a = 0; a < PPB; ++a) {
                float p1 = w_[a][0] * w_[a][1];
                float p2 = p1 * w_[a][2];
                float p3 = p2 * w_[a][3];
                float r  = __builtin_amdgcn_rcpf(p3);
                float i3 = r * p2;            // 1/w3
                float q  = r * w_[a][3];      // 1/p2
                float i2 = q * p1;            // 1/w2
                float q2 = q * w_[a][2];      // 1/p1
                float i1 = q2 * w_[a][0];     // 1/w1
                float i0 = q2 * w_[a][1];     // 1/w0
                float t;
                t = i0 * i0; acc[a] = fmaf(t * t, i0, acc[a]);
                t = i1 * i1; acc[a] = fmaf(t * t, i1, acc[a]);
                t = i2 * i2; acc[a] = fmaf(t * t, i2, acc[a]);
                t = i3 * i3; acc[a] = fmaf(t * t, i3, acc[a]);
            }
            cur = nxt;
        }

        #pragma unroll
        for (int a = 0; a < PPB; ++a) {
            float v = acc[a];
            #pragma unroll
            for (int off = 32; off; off >>= 1) v += __shfl_down(v, off, 64);
            if ((tid & 63) == 0) lred[a][tid >> 6] = v;
        }
        __syncthreads();
        if (tid < PPB) {
            float s = lred[tid][0] + lred[tid][1] + lred[tid][2] + lred[tid][3];
            atomicAdd(&ws[WS_S + p0 + tid], s);
        }
    } else {
        // ---------------- term 1: heat-weighted min distance ----------------
        const int idx = (bid - NB_T2) * 256 + tid;
        const float fi = (float)(idx >> 8);
        const float fj = (float)(idx & (WW - 1));
        const float4* pts4 = (const float4*)pts;   // uniform idx -> SGPR loads
        float m0 = 3.4e38f, m1 = 3.4e38f, m2 = 3.4e38f, m3 = 3.4e38f;
        #pragma unroll 4
        for (int i = 0; i < NP / 2; i += 4) {
            float4 q0 = pts4[i], q1 = pts4[i + 1], q2 = pts4[i + 2], q3 = pts4[i + 3];
            float dy, dx;
            dy = fi - q0.x; dx = fj - q0.y; m0 = fminf(m0, fmaf(dy, dy, dx * dx));
            dy = fi - q0.z; dx = fj - q0.w; m1 = fminf(m1, fmaf(dy, dy, dx * dx));
            dy = fi - q1.x; dx = fj - q1.y; m2 = fminf(m2, fmaf(dy, dy, dx * dx));
            dy = fi - q1.z; dx = fj - q1.w; m3 = fminf(m3, fmaf(dy, dy, dx * dx));
            dy = fi - q2.x; dx = fj - q2.y; m0 = fminf(m0, fmaf(dy, dy, dx * dx));
            dy = fi - q2.z; dx = fj - q2.w; m1 = fminf(m1, fmaf(dy, dy, dx * dx));
            dy = fi - q3.x; dx = fj - q3.y; m2 = fminf(m2, fmaf(dy, dy, dx * dx));
            dy = fi - q3.z; dx = fj - q3.w; m3 = fminf(m3, fmaf(dy, dy, dx * dx));
        }
        float mind = __builtin_amdgcn_sqrtf(fminf(fminf(m0, m1), fminf(m2, m3)));
        float h  = hm[idx];
        float v1 = h * mind;
        float v2 = fabsf(h);
        #pragma unroll
        for (int off = 32; off; off >>= 1) {
            v1 += __shfl_down(v1, off, 64);
            v2 += __shfl_down(v2, off, 64);
        }
        if ((tid & 63) == 0) { lred[0][tid >> 6] = v1; lred[1][tid >> 6] = v2; }
        __syncthreads();
        if (tid == 0) atomicAdd(&ws[WS_SUM1], lred[0][0] + lred[0][1] + lred[0][2] + lred[0][3]);
        if (tid == 1) atomicAdd(&ws[WS_SUM2], lred[1][0] + lred[1][1] + lred[1][2] + lred[1][3]);
    }

    // ---------------- completion counter; last block combines ----------------
    __threadfence();                               // release our atomics
    if (tid == 0) {
        unsigned old = atomicAdd((unsigned*)&ws[WS_CNT], 1u);
        lastflag = (old == (unsigned)(NB_TOTAL - 1)) ? 1u : 0u;
    }
    __syncthreads();
    if (lastflag) {
        __threadfence();                           // acquire
        float ssum = 0.f;
        #pragma unroll
        for (int t = 0; t < 2; ++t) {
            int p = tid + t * 256;
            float S = __hip_atomic_load(&ws[WS_S + p], __ATOMIC_RELAXED,
                                        __HIP_MEMORY_SCOPE_AGENT);
            // soft_min[p] = (S/NPIX)^(-1/5) = exp2(-0.2*log2(S/NPIX))
            ssum += exp2f(-0.2f * log2f(S * (1.f / (float)NPIX)));
        }
        #pragma unroll
        for (int off = 32; off; off >>= 1) ssum += __shfl_down(ssum, off, 64);
        if ((tid & 63) == 0) dred[tid >> 6] = ssum;
        __syncthreads();
        if (tid == 0) {
            float s1 = __hip_atomic_load(&ws[WS_SUM1], __ATOMIC_RELAXED,
                                         __HIP_MEMORY_SCOPE_AGENT);
            float s2 = __hip_atomic_load(&ws[WS_SUM2], __ATOMIC_RELAXED,
                                         __HIP_MEMORY_SCOPE_AGENT);
            float tot = dred[0] + dred[1] + dred[2] + dred[3];
            out[0] = s1 / s2 + tot * (1.f / (float)NP);
        }
    }
}

extern "C" void kernel_launch(void* const* d_in, const int* in_sizes, int n_in,
                              void* d_out, int out_size, void* d_ws, size_t ws_size,
                              hipStream_t stream) {
    const float* hm  = (const float*)d_in[0];   // (256,256) f32
    const float* pts = (const float*)d_in[1];   // (512,2)  f32
    float* ws  = (float*)d_ws;
    float* out = (float*)d_out;

    // zero accumulators + counter (ws is re-poisoned to 0xAA before every launch)
    (void)hipMemsetAsync(d_ws, 0, (WS_S + NP) * sizeof(float), stream);

    whd_fused_kernel<<<NB_TOTAL, 256, 0, stream>>>(hm, pts, ws, out);
}

// Round 5
// 77.499 us; speedup vs baseline: 2.6125x; 2.6125x over previous
//
#include <hip/hip_runtime.h>

// Problem constants (match reference)
#define HH 256
#define WW 256
#define NPIX (HH * WW)        // 65536
#define NP 512                // points
// ALPHA = -5.0, 1/ALPHA = -0.2

// term2 decomposition: each block = 4 consecutive points x one 32-row slice
#define PPB 4
#define SLICE_ROWS 32
#define NSLICES (HH / SLICE_ROWS)          // 8
#define NPGRP (NP / PPB)                   // 128
#define NB_T2 (NPGRP * NSLICES)            // 1024
#define NB_T1 (NPIX / 256)                 // 256
#define NB_TOTAL (NB_T1 + NB_T2)           // 1280  (t1 blocks first: long waves start early)

// ws float layout: [0]=SUM1  [1]=SUM2  [2..2+NP)=S[p]
#define WS_SUM1 0
#define WS_SUM2 1
#define WS_S    2

__global__ __launch_bounds__(256) void whd_main(const float* __restrict__ hm,
                                                const float* __restrict__ pts,
                                                float* __restrict__ ws) {
    const int tid = threadIdx.x;
    const int bid = blockIdx.x;
    __shared__ float sred[PPB][4];
    __shared__ float dred[4];

    if (bid < NB_T1) {
        // ---------------- term 1: heat-weighted min distance ----------------
        const int idx = bid * 256 + tid;
        const float fi = (float)(idx >> 8);
        const float fj = (float)(idx & (WW - 1));
        const float4* pts4 = (const float4*)pts;   // uniform idx -> SGPR loads
        float m0 = 3.4e38f, m1 = 3.4e38f, m2 = 3.4e38f, m3 = 3.4e38f;
        #pragma unroll 4
        for (int i = 0; i < NP / 2; i += 4) {
            float4 q0 = pts4[i], q1 = pts4[i + 1], q2 = pts4[i + 2], q3 = pts4[i + 3];
            float dy, dx;
            dy = fi - q0.x; dx = fj - q0.y; m0 = fminf(m0, fmaf(dy, dy, dx * dx));
            dy = fi - q0.z; dx = fj - q0.w; m1 = fminf(m1, fmaf(dy, dy, dx * dx));
            dy = fi - q1.x; dx = fj - q1.y; m2 = fminf(m2, fmaf(dy, dy, dx * dx));
            dy = fi - q1.z; dx = fj - q1.w; m3 = fminf(m3, fmaf(dy, dy, dx * dx));
            dy = fi - q2.x; dx = fj - q2.y; m0 = fminf(m0, fmaf(dy, dy, dx * dx));
            dy = fi - q2.z; dx = fj - q2.w; m1 = fminf(m1, fmaf(dy, dy, dx * dx));
            dy = fi - q3.x; dx = fj - q3.y; m2 = fminf(m2, fmaf(dy, dy, dx * dx));
            dy = fi - q3.z; dx = fj - q3.w; m3 = fminf(m3, fmaf(dy, dy, dx * dx));
        }
        float mind = __builtin_amdgcn_sqrtf(fminf(fminf(m0, m1), fminf(m2, m3)));
        float h  = hm[idx];
        float v1 = h * mind;
        float v2 = fabsf(h);
        #pragma unroll
        for (int off = 32; off; off >>= 1) {
            v1 += __shfl_down(v1, off, 64);
            v2 += __shfl_down(v2, off, 64);
        }
        if ((tid & 63) == 0) { sred[0][tid >> 6] = v1; sred[1][tid >> 6] = v2; }
        __syncthreads();
        if (tid == 0) atomicAdd(&ws[WS_SUM1], sred[0][0] + sred[0][1] + sred[0][2] + sred[0][3]);
        if (tid == 1) atomicAdd(&ws[WS_SUM2], sred[1][0] + sred[1][1] + sred[1][2] + sred[1][3]);
    } else {
        // ---------------- term 2: soft-min accumulation ----------------
        const int b2 = bid - NB_T1;
        // dmax recomputed per block (cheap): max over the integer grid is at a
        // corner; d^2 separable.
        float m = 0.f;
        #pragma unroll
        for (int t = 0; t < 2; ++t) {
            int p = tid + t * 256;
            float py = pts[2 * p], px = pts[2 * p + 1];
            float my = fmaxf(py * py, (255.f - py) * (255.f - py));
            float mx = fmaxf(px * px, (255.f - px) * (255.f - px));
            m = fmaxf(m, my + mx);
        }
        #pragma unroll
        for (int off = 32; off; off >>= 1) m = fmaxf(m, __shfl_down(m, off, 64));
        if ((tid & 63) == 0) dred[tid >> 6] = m;
        __syncthreads();
        const float dmax = __builtin_amdgcn_sqrtf(
            fmaxf(fmaxf(dred[0], dred[1]), fmaxf(dred[2], dred[3])));

        const int pgrp  = b2 & (NPGRP - 1);
        const int slice = b2 >> 7;             // NPGRP = 128
        const int p0    = pgrp * PPB;

        float py[PPB], px[PPB];
        #pragma unroll
        for (int a = 0; a < PPB; ++a) {        // uniform -> SGPR loads
            py[a] = pts[2 * (p0 + a)];
            px[a] = pts[2 * (p0 + a) + 1];
        }

        // thread owns cols col0..col0+3 of rows {slice*32 + (tid>>6) + 4k}
        const float col0 = (float)((tid & 63) << 2);
        float dx2[PPB][4];
        #pragma unroll
        for (int a = 0; a < PPB; ++a)
            #pragma unroll
            for (int c = 0; c < 4; ++c) {
                float dx = col0 + (float)c - px[a];
                dx2[a][c] = dx * dx;
            }

        const float4* hm4 = (const float4*)hm;
        const int   gbase   = slice * (SLICE_ROWS * WW / 4) + tid;
        const float rowbase = (float)(slice * SLICE_ROWS + (tid >> 6));
        float acc[PPB] = {0.f, 0.f, 0.f, 0.f};

        #pragma unroll
        for (int k = 0; k < 8; ++k) {
            float4 h4 = hm4[gbase + k * 256];          // independent, compiler pipelines
            const float row = rowbase + (float)(4 * k);
            const float hx[4] = {h4.x, h4.y, h4.z, h4.w};
            float ct[4];
            #pragma unroll
            for (int c = 0; c < 4; ++c) ct[c] = fmaf(-hx[c], dmax, dmax); // (1-h)*dmax

            #pragma unroll
            for (int a = 0; a < PPB; ++a) {
                float dy = row - py[a];
                float dy2 = dy * dy;
                // 4 distances (independent v_sqrt), 4 weights
                float w0 = fmaf(hx[0], __builtin_amdgcn_sqrtf(dy2 + dx2[a][0]), ct[0]);
                float w1 = fmaf(hx[1], __builtin_amdgcn_sqrtf(dy2 + dx2[a][1]), ct[1]);
                float w2 = fmaf(hx[2], __builtin_amdgcn_sqrtf(dy2 + dx2[a][2]), ct[2]);
                float w3 = fmaf(hx[3], __builtin_amdgcn_sqrtf(dy2 + dx2[a][3]), ct[3]);
                // Montgomery batch inversion: 4 inverses from 1 v_rcp
                float p1 = w0 * w1;
                float p2 = p1 * w2;
                float p3 = p2 * w3;
                float r  = __builtin_amdgcn_rcpf(p3);
                float i3 = r * p2;           // 1/w3
                float q  = r * w3;           // 1/p2
                float i2 = q * p1;           // 1/w2
                float q2 = q * w2;           // 1/p1
                float i1 = q2 * w0;          // 1/w1
                float i0 = q2 * w1;          // 1/w0
                float t;
                t = i0 * i0; acc[a] = fmaf(t * t, i0, acc[a]);
                t = i1 * i1; acc[a] = fmaf(t * t, i1, acc[a]);
                t = i2 * i2; acc[a] = fmaf(t * t, i2, acc[a]);
                t = i3 * i3; acc[a] = fmaf(t * t, i3, acc[a]);
            }
        }

        #pragma unroll
        for (int a = 0; a < PPB; ++a) {
            float v = acc[a];
            #pragma unroll
            for (int off = 32; off; off >>= 1) v += __shfl_down(v, off, 64);
            if ((tid & 63) == 0) sred[a][tid >> 6] = v;
        }
        __syncthreads();
        if (tid < PPB) {
            float s = sred[tid][0] + sred[tid][1] + sred[tid][2] + sred[tid][3];
            atomicAdd(&ws[WS_S + p0 + tid], s);
        }
    }
}

// ---------------------------------------------------------------------------
// Final combine: kernel boundary guarantees visibility of all atomics.
// ---------------------------------------------------------------------------
__global__ __launch_bounds__(NP) void whd_final(const float* __restrict__ ws,
                                                float* __restrict__ out) {
    const int t = threadIdx.x;  // 0..511
    float S = ws[WS_S + t];
    // soft_min[p] = (S/NPIX)^(-1/5) = exp2(-0.2*log2(S/NPIX))
    float sm = exp2f(-0.2f * log2f(S * (1.f / (float)NPIX)));
    #pragma unroll
    for (int off = 32; off; off >>= 1) sm += __shfl_down(sm, off, 64);
    __shared__ float red[8];
    if ((t & 63) == 0) red[t >> 6] = sm;
    __syncthreads();
    if (t == 0) {
        float s = 0.f;
        #pragma unroll
        for (int w = 0; w < 8; ++w) s += red[w];
        out[0] = ws[WS_SUM1] / ws[WS_SUM2] + s * (1.f / (float)NP);
    }
}

extern "C" void kernel_launch(void* const* d_in, const int* in_sizes, int n_in,
                              void* d_out, int out_size, void* d_ws, size_t ws_size,
                              hipStream_t stream) {
    const float* hm  = (const float*)d_in[0];   // (256,256) f32
    const float* pts = (const float*)d_in[1];   // (512,2)  f32
    float* ws  = (float*)d_ws;
    float* out = (float*)d_out;

    // zero accumulators (ws is re-poisoned to 0xAA before every launch)
    (void)hipMemsetAsync(d_ws, 0, (WS_S + NP) * sizeof(float), stream);

    whd_main <<<NB_TOTAL, 256, 0, stream>>>(hm, pts, ws);
    whd_final<<<1,        NP,  0, stream>>>(ws, out);
}

// Round 6
// 70.475 us; speedup vs baseline: 2.8729x; 1.0997x over previous
//
#include <hip/hip_runtime.h>

// Problem constants (match reference)
#define HH 256
#define WW 256
#define NPIX (HH * WW)        // 65536
#define NP 512                // points
// ALPHA = -5.0, 1/ALPHA = -0.2

// term2 decomposition: each block = 4 consecutive points x one 32-row slice
#define PPB 4
#define SLICE_ROWS 32
#define NSLICES (HH / SLICE_ROWS)          // 8
#define NPGRP (NP / PPB)                   // 128
#define NB_T2 (NPGRP * NSLICES)            // 1024
#define NB_T1 (NPIX / 256)                 // 256
#define NB_TOTAL (NB_T1 + NB_T2)           // 1280  (t1 first: longest blocks start early)

// ws float layout (NO memset needed - every slot read by final is written by main):
//   [0 .. 4096)          S-partials: ws[p*8 + slice]
//   [4096 .. 4352)       term1 v1 partials (per t1 block)
//   [4352 .. 4608)       term1 v2 partials
#define WS_SP   0
#define WS_T1A  (NP * NSLICES)             // 4096
#define WS_T1B  (WS_T1A + NB_T1)           // 4352

__global__ __launch_bounds__(256) void whd_main(const float* __restrict__ hm,
                                                const float* __restrict__ pts,
                                                float* __restrict__ ws) {
    const int tid = threadIdx.x;
    const int bid = blockIdx.x;
    __shared__ float sred[PPB][4];
    __shared__ float dred[4];

    if (bid < NB_T1) {
        // ---------------- term 1: heat-weighted min distance ----------------
        const int idx = bid * 256 + tid;
        const float fi = (float)(idx >> 8);
        const float fj = (float)(idx & (WW - 1));
        const float4* pts4 = (const float4*)pts;   // uniform idx -> SGPR loads
        float m0 = 3.4e38f, m1 = 3.4e38f, m2 = 3.4e38f, m3 = 3.4e38f;
        #pragma unroll 4
        for (int i = 0; i < NP / 2; i += 4) {
            float4 q0 = pts4[i], q1 = pts4[i + 1], q2 = pts4[i + 2], q3 = pts4[i + 3];
            float dy, dx;
            dy = fi - q0.x; dx = fj - q0.y; m0 = fminf(m0, fmaf(dy, dy, dx * dx));
            dy = fi - q0.z; dx = fj - q0.w; m1 = fminf(m1, fmaf(dy, dy, dx * dx));
            dy = fi - q1.x; dx = fj - q1.y; m2 = fminf(m2, fmaf(dy, dy, dx * dx));
            dy = fi - q1.z; dx = fj - q1.w; m3 = fminf(m3, fmaf(dy, dy, dx * dx));
            dy = fi - q2.x; dx = fj - q2.y; m0 = fminf(m0, fmaf(dy, dy, dx * dx));
            dy = fi - q2.z; dx = fj - q2.w; m1 = fminf(m1, fmaf(dy, dy, dx * dx));
            dy = fi - q3.x; dx = fj - q3.y; m2 = fminf(m2, fmaf(dy, dy, dx * dx));
            dy = fi - q3.z; dx = fj - q3.w; m3 = fminf(m3, fmaf(dy, dy, dx * dx));
        }
        float mind = __builtin_amdgcn_sqrtf(fminf(fminf(m0, m1), fminf(m2, m3)));
        float h  = hm[idx];
        float v1 = h * mind;
        float v2 = fabsf(h);
        #pragma unroll
        for (int off = 32; off; off >>= 1) {
            v1 += __shfl_down(v1, off, 64);
            v2 += __shfl_down(v2, off, 64);
        }
        if ((tid & 63) == 0) { sred[0][tid >> 6] = v1; sred[1][tid >> 6] = v2; }
        __syncthreads();
        if (tid == 0) ws[WS_T1A + bid] = sred[0][0] + sred[0][1] + sred[0][2] + sred[0][3];
        if (tid == 1) ws[WS_T1B + bid] = sred[1][0] + sred[1][1] + sred[1][2] + sred[1][3];
    } else {
        // ---------------- term 2: soft-min accumulation ----------------
        const int b2 = bid - NB_T1;
        // dmax recomputed per block (cheap): grid max is at a corner; d^2 separable.
        float m = 0.f;
        #pragma unroll
        for (int t = 0; t < 2; ++t) {
            int p = tid + t * 256;
            float py = pts[2 * p], px = pts[2 * p + 1];
            float my = fmaxf(py * py, (255.f - py) * (255.f - py));
            float mx = fmaxf(px * px, (255.f - px) * (255.f - px));
            m = fmaxf(m, my + mx);
        }
        #pragma unroll
        for (int off = 32; off; off >>= 1) m = fmaxf(m, __shfl_down(m, off, 64));
        if ((tid & 63) == 0) dred[tid >> 6] = m;
        __syncthreads();
        const float dmax = __builtin_amdgcn_sqrtf(
            fmaxf(fmaxf(dred[0], dred[1]), fmaxf(dred[2], dred[3])));

        const int pgrp  = b2 & (NPGRP - 1);
        const int slice = b2 >> 7;             // NPGRP = 128
        const int p0    = pgrp * PPB;

        float py[PPB], px[PPB];
        #pragma unroll
        for (int a = 0; a < PPB; ++a) {        // uniform -> SGPR loads
            py[a] = pts[2 * (p0 + a)];
            px[a] = pts[2 * (p0 + a) + 1];
        }

        // thread owns cols col0..col0+3 of rows {slice*32 + (tid>>6) + 4k}
        const float col0 = (float)((tid & 63) << 2);
        float dx2[PPB][4];
        #pragma unroll
        for (int a = 0; a < PPB; ++a)
            #pragma unroll
            for (int c = 0; c < 4; ++c) {
                float dx = col0 + (float)c - px[a];
                dx2[a][c] = dx * dx;
            }

        const float4* hm4 = (const float4*)hm;
        const int   gbase   = slice * (SLICE_ROWS * WW / 4) + tid;
        const float rowbase = (float)(slice * SLICE_ROWS + (tid >> 6));
        float acc[PPB] = {0.f, 0.f, 0.f, 0.f};

        #pragma unroll
        for (int k = 0; k < 8; ++k) {
            float4 h4 = hm4[gbase + k * 256];          // independent loads, pipeline
            const float row = rowbase + (float)(4 * k);
            const float hx[4] = {h4.x, h4.y, h4.z, h4.w};
            float ct[4];
            #pragma unroll
            for (int c = 0; c < 4; ++c) ct[c] = fmaf(-hx[c], dmax, dmax); // (1-h)*dmax
            float dy2[PPB];
            #pragma unroll
            for (int a = 0; a < PPB; ++a) { float dy = row - py[a]; dy2[a] = dy * dy; }

            // 16 fully-independent 7-op chains: add->sqrt->fma->rcp->mul->mul->fma
            #pragma unroll
            for (int a = 0; a < PPB; ++a) {
                #pragma unroll
                for (int c = 0; c < 4; ++c) {
                    float d  = __builtin_amdgcn_sqrtf(dy2[a] + dx2[a][c]);
                    float w  = fmaf(hx[c], d, ct[c]);          // hm*d + (1-hm)*dmax
                    float r  = __builtin_amdgcn_rcpf(w);
                    float r2 = r * r;
                    acc[a]   = fmaf(r2 * r2, r, acc[a]);       // += w^-5
                }
            }
        }

        #pragma unroll
        for (int a = 0; a < PPB; ++a) {
            float v = acc[a];
            #pragma unroll
            for (int off = 32; off; off >>= 1) v += __shfl_down(v, off, 64);
            if ((tid & 63) == 0) sred[a][tid >> 6] = v;
        }
        __syncthreads();
        if (tid < PPB) {
            ws[WS_SP + (p0 + tid) * NSLICES + slice] =
                sred[tid][0] + sred[tid][1] + sred[tid][2] + sred[tid][3];
        }
    }
}

// ---------------------------------------------------------------------------
// Final combine (1 block): kernel boundary guarantees visibility of partials.
// ---------------------------------------------------------------------------
__global__ __launch_bounds__(NP) void whd_final(const float* __restrict__ ws,
                                                float* __restrict__ out) {
    const int t = threadIdx.x;  // 0..511
    // S[p] = sum of 8 slice partials (two contiguous float4 loads)
    const float4* w4 = (const float4*)(ws + WS_SP);
    float4 a = w4[t * 2], b = w4[t * 2 + 1];
    float S = ((a.x + a.y) + (a.z + a.w)) + ((b.x + b.y) + (b.z + b.w));
    // soft_min[p] = (S/NPIX)^(-1/5) = exp2(-0.2*log2(S/NPIX))
    float sm = exp2f(-0.2f * log2f(S * (1.f / (float)NPIX)));
    // term1 partials (first 256 threads carry them)
    float v1 = (t < NB_T1) ? ws[WS_T1A + t] : 0.f;
    float v2 = (t < NB_T1) ? ws[WS_T1B + t] : 0.f;

    #pragma unroll
    for (int off = 32; off; off >>= 1) {
        sm += __shfl_down(sm, off, 64);
        v1 += __shfl_down(v1, off, 64);
        v2 += __shfl_down(v2, off, 64);
    }
    __shared__ float red[3][8];
    if ((t & 63) == 0) { int w = t >> 6; red[0][w] = sm; red[1][w] = v1; red[2][w] = v2; }
    __syncthreads();
    if (t == 0) {
        float rsm = 0.f, r1 = 0.f, r2 = 0.f;
        #pragma unroll
        for (int w = 0; w < 8; ++w) { rsm += red[0][w]; r1 += red[1][w]; r2 += red[2][w]; }
        out[0] = r1 / r2 + rsm * (1.f / (float)NP);
    }
}

extern "C" void kernel_launch(void* const* d_in, const int* in_sizes, int n_in,
                              void* d_out, int out_size, void* d_ws, size_t ws_size,
                              hipStream_t stream) {
    const float* hm  = (const float*)d_in[0];   // (256,256) f32
    const float* pts = (const float*)d_in[1];   // (512,2)  f32
    float* ws  = (float*)d_ws;
    float* out = (float*)d_out;

    // no memset: every ws slot consumed by whd_final is written by whd_main
    whd_main <<<NB_TOTAL, 256, 0, stream>>>(hm, pts, ws);
    whd_final<<<1,        NP,  0, stream>>>(ws, out);
}